// Round 17
// baseline (129.502 us; speedup 1.0000x reference)
//
#include <hip/hip_runtime.h>
#include <hip/hip_bf16.h>

typedef __attribute__((ext_vector_type(8))) short bf16x8;
typedef __attribute__((ext_vector_type(4))) float f32x4;
typedef __attribute__((ext_vector_type(8))) unsigned short ushort8;

#define HW 4096
#define NC 64
#define PROWS 4356  // 66*66 padded rows

static __device__ __forceinline__ unsigned short f2bf(float f) {
    unsigned int u = __float_as_uint(f);
    unsigned int r = (u + 0x7FFFu + ((u >> 16) & 1u)) >> 16;
    return (unsigned short)r;
}

// ---------------- init: zero inP + convert proj weights to bf16 [tap][oc][ic]
__global__ __launch_bounds__(256) void k_init(float4* __restrict__ p, int n4,
                                              const float* __restrict__ wp,
                                              unsigned short* __restrict__ wbf) {
    int bx = blockIdx.x;
    int t = threadIdx.x;
    if (bx < 545) {
        int i = bx * 256 + t;
        if (i < n4) p[i] = make_float4(0.f, 0.f, 0.f, 0.f);
    } else {
        int idx = (bx - 545) * 256 + t;  // 36864 total
        int tap = idx >> 12;
        int rem = idx & 4095;
        int oc = rem >> 6, ic = rem & 63;
        wbf[idx] = f2bf(wp[(oc * 64 + ic) * 9 + tap]);
    }
}

// ---------------- conv 1x1: qkv_raw[b][oc][n] = sum_ic w[oc][ic]*x[b][ic][n]
__global__ __launch_bounds__(256) void k_conv1x1(const float* __restrict__ x,
                                                 const float* __restrict__ wqkv,
                                                 float* __restrict__ out) {
    __shared__ float wl[512]; // 8 oc x 64 ic
    int nb = blockIdx.x, ocg = blockIdx.y, b = blockIdx.z;
    int t = threadIdx.x;
    for (int i = t; i < 512; i += 256) wl[i] = wqkv[ocg * 512 + i];
    __syncthreads();
    int n = nb * 256 + t;
    const float* xb = x + (size_t)b * NC * HW + n;
    float acc[8] = {0.f,0.f,0.f,0.f,0.f,0.f,0.f,0.f};
    for (int ic = 0; ic < 64; ic++) {
        float xv = xb[(size_t)ic * HW];
        #pragma unroll
        for (int o = 0; o < 8; o++) acc[o] += wl[o * 64 + ic] * xv;
    }
    float* ob = out + (size_t)b * 192 * HW + (size_t)(ocg * 8) * HW + n;
    #pragma unroll
    for (int o = 0; o < 8; o++) ob[(size_t)o * HW] = acc[o];
}

// ---------------- depthwise 3x3 SAME + per-channel partial sum of squares (q,k)
__global__ __launch_bounds__(256) void k_dwconv(const float* __restrict__ in,
                                                const float* __restrict__ wdw,
                                                float* __restrict__ out,
                                                float* __restrict__ psq) {
    int yg = blockIdx.x, ch = blockIdx.y, b = blockIdx.z;
    int t = threadIdx.x;
    int y = yg * 4 + (t >> 6), xx = t & 63;
    const float* ib = in + ((size_t)b * 192 + ch) * HW;
    const float* wp = wdw + ch * 9;
    float s = 0.f;
    #pragma unroll
    for (int dy = 0; dy < 3; dy++) {
        int yy = y + dy - 1;
        if (yy < 0 || yy > 63) continue;
        const float* r = ib + yy * 64;
        float v0 = (xx > 0) ? r[xx - 1] : 0.f;
        float v1 = r[xx];
        float v2 = (xx < 63) ? r[xx + 1] : 0.f;
        const float* wr = wp + dy * 3;
        s += wr[0] * v0 + wr[1] * v1 + wr[2] * v2;
    }
    out[((size_t)b * 192 + ch) * HW + y * 64 + xx] = s;
    if (ch < 128) {
        float sq = s * s;
        #pragma unroll
        for (int m = 1; m < 64; m <<= 1) sq += __shfl_xor(sq, m);
        __shared__ float red[4];
        if ((t & 63) == 0) red[t >> 6] = sq;
        __syncthreads();
        if (t == 0)
            psq[((size_t)b * 128 + ch) * 16 + yg] = red[0] + red[1] + red[2] + red[3];
    }
}

// ---------------- combined K-side scale: wk[b][c] = log2e / (max(|q_c|,eps)*max(|k_c|,eps))
__global__ __launch_bounds__(256) void k_scales(const float* __restrict__ psq,
                                                float* __restrict__ wk) {
    int i = threadIdx.x;  // 256 = 4 b x 64 c
    int b = i >> 6, c = i & 63;
    const float* pq = psq + ((size_t)b * 128 + c) * 16;
    const float* pk = psq + ((size_t)b * 128 + 64 + c) * 16;
    float sq = 0.f, sk = 0.f;
    #pragma unroll
    for (int j = 0; j < 16; j++) { sq += pq[j]; sk += pk[j]; }
    float nq = fmaxf(sqrtf(sq), 1e-12f);
    float nk = fmaxf(sqrtf(sk), 1e-12f);
    wk[i] = 1.4426950408889634f / (nq * nk);
}

// ---------------- pack: qT raw bf16 [b][n][c]; kT scaled by wk; vn [b][c][n]
__global__ __launch_bounds__(256) void k_pack(const float* __restrict__ qkv,
                                              const float* __restrict__ wk,
                                              unsigned short* __restrict__ qT,
                                              unsigned short* __restrict__ kT,
                                              unsigned short* __restrict__ vn) {
    int nb = blockIdx.x, sel = blockIdx.y, b = blockIdx.z;
    int n = nb * 256 + threadIdx.x;
    if (sel == 2) {
        const float* src = qkv + ((size_t)b * 192 + 128) * HW + n;
        unsigned short* dst = vn + (size_t)b * NC * HW + n;
        for (int c = 0; c < 64; c++) dst[(size_t)c * HW] = f2bf(src[(size_t)c * HW]);
    } else if (sel == 0) {
        const float* src = qkv + (size_t)b * 192 * HW + n;
        unsigned short* dst = qT + ((size_t)b * HW + n) * NC;
        for (int c0 = 0; c0 < 64; c0 += 8) {
            ushort8 pk;
            #pragma unroll
            for (int j = 0; j < 8; j++) pk[j] = f2bf(src[(size_t)(c0 + j) * HW]);
            *reinterpret_cast<ushort8*>(dst + c0) = pk;
        }
    } else {
        const float* src = qkv + ((size_t)b * 192 + 64) * HW + n;
        const float* wv = wk + b * 64;
        unsigned short* dst = kT + ((size_t)b * HW + n) * NC;
        for (int c0 = 0; c0 < 64; c0 += 8) {
            ushort8 pk;
            #pragma unroll
            for (int j = 0; j < 8; j++)
                pk[j] = f2bf(src[(size_t)(c0 + j) * HW] * wv[c0 + j]);
            *reinterpret_cast<ushort8*>(dst + c0) = pk;
        }
    }
}

// ---------------- pass 1: D[m] = sum_n exp2(s'[m,n]); K-tile double-buffered LDS.
// 1D grid (1024) with XCD-aware decode: batch pinned to an XCD pair -> L2-resident.
__global__ __launch_bounds__(256) void k_rowsum(const unsigned short* __restrict__ qT,
                                                const unsigned short* __restrict__ kT,
                                                float* __restrict__ part) {
    __shared__ __align__(16) unsigned short klds[2][64 * 72];
    int i = blockIdx.x;
    int b = (i >> 1) & 3;
    int mblk = (i >> 3) & 31;
    int ns = ((i >> 8) & 3) * 2 + (i & 1);
    int t = threadIdx.x;
    int w = t >> 6, lane = t & 63, g = lane >> 4, r15 = lane & 15;
    const unsigned short* qb = qT + (size_t)b * HW * NC;
    const unsigned short* kb = kT + (size_t)b * HW * NC;
    int m0 = mblk * 128 + w * 16;
    const unsigned short* qp0 = qb + (size_t)(m0 + r15) * NC + g * 8;
    const unsigned short* qp1 = qb + (size_t)(m0 + 64 + r15) * NC + g * 8;
    bf16x8 a0 = *reinterpret_cast<const bf16x8*>(qp0);
    bf16x8 a1 = *reinterpret_cast<const bf16x8*>(qp0 + 32);
    bf16x8 a2 = *reinterpret_cast<const bf16x8*>(qp1);
    bf16x8 a3 = *reinterpret_cast<const bf16x8*>(qp1 + 32);
    float sa[4] = {0.f, 0.f, 0.f, 0.f};
    float sb[4] = {0.f, 0.f, 0.f, 0.f};
    int nbase = ns * 512;
    int nl = t >> 2, seg = t & 3;
    {
        const unsigned short* sp = kb + (size_t)(nbase + nl) * NC + seg * 16;
        *reinterpret_cast<ushort8*>(&klds[0][nl * 72 + seg * 16]) = *reinterpret_cast<const ushort8*>(sp);
        *reinterpret_cast<ushort8*>(&klds[0][nl * 72 + seg * 16 + 8]) = *reinterpret_cast<const ushort8*>(sp + 8);
    }
    __syncthreads();
    int cur = 0;
    for (int it = 0; it < 8; it++) {
        ushort8 r0, r1;
        bool hasnext = it < 7;
        if (hasnext) {
            const unsigned short* sp = kb + (size_t)(nbase + (it + 1) * 64 + nl) * NC + seg * 16;
            r0 = *reinterpret_cast<const ushort8*>(sp);
            r1 = *reinterpret_cast<const ushort8*>(sp + 8);
        }
        #pragma unroll
        for (int tt = 0; tt < 4; tt++) {
            const unsigned short* kp = &klds[cur][(tt * 16 + r15) * 72 + g * 8];
            bf16x8 b0 = *reinterpret_cast<const bf16x8*>(kp);
            bf16x8 b1 = *reinterpret_cast<const bf16x8*>(kp + 32);
            f32x4 d0 = {0.f, 0.f, 0.f, 0.f};
            f32x4 d1 = {0.f, 0.f, 0.f, 0.f};
            d0 = __builtin_amdgcn_mfma_f32_16x16x32_bf16(a0, b0, d0, 0, 0, 0);
            d1 = __builtin_amdgcn_mfma_f32_16x16x32_bf16(a2, b0, d1, 0, 0, 0);
            d0 = __builtin_amdgcn_mfma_f32_16x16x32_bf16(a1, b1, d0, 0, 0, 0);
            d1 = __builtin_amdgcn_mfma_f32_16x16x32_bf16(a3, b1, d1, 0, 0, 0);
            #pragma unroll
            for (int r = 0; r < 4; r++) {
                sa[r] += __builtin_amdgcn_exp2f(d0[r]);
                sb[r] += __builtin_amdgcn_exp2f(d1[r]);
            }
        }
        if (hasnext) {
            *reinterpret_cast<ushort8*>(&klds[cur ^ 1][nl * 72 + seg * 16]) = r0;
            *reinterpret_cast<ushort8*>(&klds[cur ^ 1][nl * 72 + seg * 16 + 8]) = r1;
            cur ^= 1;
        }
        __syncthreads();
    }
    #pragma unroll
    for (int off = 1; off < 16; off <<= 1) {
        #pragma unroll
        for (int r = 0; r < 4; r++) {
            sa[r] += __shfl_xor(sa[r], off);
            sb[r] += __shfl_xor(sb[r], off);
        }
    }
    if (r15 == 0) {
        size_t base = ((size_t)ns * 4 + b) * HW;
        f32x4 va = {sa[0], sa[1], sa[2], sa[3]};
        f32x4 vb = {sb[0], sb[1], sb[2], sb[3]};
        *reinterpret_cast<f32x4*>(&part[base + m0 + g * 4]) = va;
        *reinterpret_cast<f32x4*>(&part[base + m0 + 64 + g * 4]) = vb;
    }
}

// ---------------- l2i[m] = -log2(D[m]) (folds softmax denom into MFMA C-init)
__global__ __launch_bounds__(256) void k_l2i(const float* __restrict__ part,
                                             float* __restrict__ l2i) {
    int i = blockIdx.x * 256 + threadIdx.x;  // 16384 = 4*HW
    float s = 0.f;
    #pragma unroll
    for (int ns = 0; ns < 8; ns++) s += part[i + ns * 4 * HW];
    l2i[i] = -log2f(s);
}

// ---------------- fused pass 2 (barrier-free, 64-col x 32-channel blocks):
// ct-split: each block owns 32 output channels -> acc 32 AGPR (was 64) -> ~116
// regs/thread -> 4 waves/SIMD. S-phase duplicated across the 2 channel-halves
// (channel-independent; MFMA pipe has headroom). Body otherwise identical to the
// R15-proven 64-col kernel. XCD decode pins batch to an XCD pair.
__global__ __launch_bounds__(512, 2) void k_attn_fused(const unsigned short* __restrict__ qT,
                                                       const unsigned short* __restrict__ kT,
                                                       const unsigned short* __restrict__ vn,
                                                       const float* __restrict__ l2i,
                                                       unsigned short* __restrict__ inP) {
    __shared__ float red[8][64][8];  // 16 KB epilogue reduce
    int i = blockIdx.x;
    int b = (i >> 1) & 3;                 // XCD-pair pinned batch
    int j = ((i >> 3) << 1) | (i & 1);    // [0,128): 64 col-tiles x 2 ch-halves
    int nb = j >> 1;
    int ch = j & 1;
    int t = threadIdx.x;
    int w = t >> 6, lane = t & 63, g = lane >> 4, r15 = lane & 15;
    int n0 = nb * 64;
    int c_base = ch * 32;
    const unsigned short* qb = qT + (size_t)b * HW * NC;
    const unsigned short* kbp = kT + (size_t)b * HW * NC;
    const unsigned short* vb = vn + (size_t)b * NC * HW;
    const float* rib = l2i + (size_t)b * HW;
    // K-fragments resident in registers (shared across waves -> L1 hits)
    bf16x8 kf0[4], kf1[4];
    #pragma unroll
    for (int tt = 0; tt < 4; tt++) {
        const unsigned short* kp = kbp + (size_t)(n0 + tt * 16 + r15) * NC + g * 8;
        kf0[tt] = *reinterpret_cast<const bf16x8*>(kp);
        kf1[tt] = *reinterpret_cast<const bf16x8*>(kp + 32);
    }
    f32x4 acc[2][4];
    #pragma unroll
    for (int ct = 0; ct < 2; ct++)
        #pragma unroll
        for (int tt = 0; tt < 4; tt++) acc[ct][tt] = f32x4{0.f, 0.f, 0.f, 0.f};
    int mw = w * 32;
    // permuted Q row: S-tile ts loads m = base + (r15>>2)*8 + ts*4 + (r15&3)
    int qrow = (r15 >> 2) * 8 + (r15 & 3);
    const unsigned short* qrp = qb + (size_t)(mw + qrow) * NC;
    bf16x8 qa[2][2];
    #pragma unroll
    for (int ts = 0; ts < 2; ts++) {
        qa[ts][0] = *reinterpret_cast<const bf16x8*>(qrp + ts * 4 * NC + g * 8);
        qa[ts][1] = *reinterpret_cast<const bf16x8*>(qrp + ts * 4 * NC + 32 + g * 8);
    }
    f32x4 iv0 = *reinterpret_cast<const f32x4*>(rib + mw + g * 8);
    f32x4 iv1 = *reinterpret_cast<const f32x4*>(rib + mw + g * 8 + 4);
    for (int it = 0; it < 16; it++) {
        int mb = it * 256;
        // V fragments for current iter (this block's 32 channels only)
        bf16x8 va[2];
        #pragma unroll
        for (int ct = 0; ct < 2; ct++)
            va[ct] = *reinterpret_cast<const bf16x8*>(vb + (size_t)(c_base + ct * 16 + r15) * HW + mb + mw + g * 8);
        // prefetch next-iter Q and l2i (latency hidden under S+PV compute)
        int adv = (it < 15) ? 256 : 0;
        const unsigned short* qrn = qrp + (size_t)adv * NC;
        bf16x8 qn[2][2];
        #pragma unroll
        for (int ts = 0; ts < 2; ts++) {
            qn[ts][0] = *reinterpret_cast<const bf16x8*>(qrn + ts * 4 * NC + g * 8);
            qn[ts][1] = *reinterpret_cast<const bf16x8*>(qrn + ts * 4 * NC + 32 + g * 8);
        }
        f32x4 ivn0 = *reinterpret_cast<const f32x4*>(rib + mb + adv + mw + g * 8);
        f32x4 ivn1 = *reinterpret_cast<const f32x4*>(rib + mb + adv + mw + g * 8 + 4);
        // S phase: C-init = l2i -> P = exp2(s' + l2i); lane-local D rows map to m = g*8 + ts*4 + r
        bf16x8 pb[4];
        #pragma unroll
        for (int tt = 0; tt < 4; tt++) {
            f32x4 d0 = __builtin_amdgcn_mfma_f32_16x16x32_bf16(qa[0][0], kf0[tt], iv0, 0, 0, 0);
            d0 = __builtin_amdgcn_mfma_f32_16x16x32_bf16(qa[0][1], kf1[tt], d0, 0, 0, 0);
            f32x4 d1 = __builtin_amdgcn_mfma_f32_16x16x32_bf16(qa[1][0], kf0[tt], iv1, 0, 0, 0);
            d1 = __builtin_amdgcn_mfma_f32_16x16x32_bf16(qa[1][1], kf1[tt], d1, 0, 0, 0);
            float e0 = exp2f(d0[0]);
            float e1 = exp2f(d0[1]);
            float e2 = exp2f(d0[2]);
            float e3 = exp2f(d0[3]);
            float f0 = exp2f(d1[0]);
            float f1 = exp2f(d1[1]);
            float f2 = exp2f(d1[2]);
            float f3 = exp2f(d1[3]);
            unsigned int p0, p1, p2, p3;
            asm("v_cvt_pk_bf16_f32 %0, %1, %2" : "=v"(p0) : "v"(e0), "v"(e1));
            asm("v_cvt_pk_bf16_f32 %0, %1, %2" : "=v"(p1) : "v"(e2), "v"(e3));
            asm("v_cvt_pk_bf16_f32 %0, %1, %2" : "=v"(p2) : "v"(f0), "v"(f1));
            asm("v_cvt_pk_bf16_f32 %0, %1, %2" : "=v"(p3) : "v"(f2), "v"(f3));
            union { unsigned int u[4]; bf16x8 v; } pu;
            pu.u[0] = p0; pu.u[1] = p1; pu.u[2] = p2; pu.u[3] = p3;
            pb[tt] = pu.v;
        }
        // PV phase: this block's 32 channels
        #pragma unroll
        for (int ct = 0; ct < 2; ct++)
            #pragma unroll
            for (int tt = 0; tt < 4; tt++)
                acc[ct][tt] = __builtin_amdgcn_mfma_f32_16x16x32_bf16(va[ct], pb[tt], acc[ct][tt], 0, 0, 0);
        #pragma unroll
        for (int ts = 0; ts < 2; ts++) { qa[ts][0] = qn[ts][0]; qa[ts][1] = qn[ts][1]; }
        iv0 = ivn0; iv1 = ivn1;
        qrp += (size_t)adv * NC;
    }
    // cross-wave reduce (8 partial sums) + bf16 store into padded transposed inP
    #pragma unroll
    for (int ph = 0; ph < 4; ph++) {
        int ct = ph >> 1, th = ph & 1;
        *reinterpret_cast<f32x4*>(&red[w][lane][0]) = acc[ct][th * 2];
        *reinterpret_cast<f32x4*>(&red[w][lane][4]) = acc[ct][th * 2 + 1];
        __syncthreads();
        int lr = t >> 3, kk = t & 7;
        float s = 0.f;
        #pragma unroll
        for (int ww = 0; ww < 8; ww++) s += red[ww][lr][kk];
        int c = c_base + ct * 16 + ((lr >> 4) << 2) + (kk & 3);
        int nn = n0 + (th * 2 + (kk >> 2)) * 16 + (lr & 15);
        int y = nn >> 6, xx = nn & 63;
        inP[((size_t)b * PROWS + (size_t)(y + 1) * 66 + 1 + xx) * 64 + c] = f2bf(s);
        __syncthreads();
    }
}

// ---------------- proj conv 3x3 via MFMA: 9 shifted GEMMs
__global__ __launch_bounds__(256) void k_proj_mfma(const unsigned short* __restrict__ inP,
                                                   const unsigned short* __restrict__ wbf,
                                                   float* __restrict__ out) {
    int nb = blockIdx.x, b = blockIdx.y;
    int t = threadIdx.x;
    int w = t >> 6, lane = t & 63, g = lane >> 4, r15 = lane & 15;
    int y = nb >> 1;
    int x0 = (nb & 1) * 32 + (w & 1) * 16;
    int oc0 = (w >> 1) * 32;
    const unsigned short* base = inP + (size_t)b * PROWS * 64;
    f32x4 acc[2] = {{0.f,0.f,0.f,0.f},{0.f,0.f,0.f,0.f}};
    #pragma unroll
    for (int tap = 0; tap < 9; tap++) {
        int dy = tap / 3, dx = tap % 3;
        int p = (y + dy) * 66 + x0 + dx + r15;
        const unsigned short* bp = base + (size_t)p * 64 + g * 8;
        bf16x8 b0 = *reinterpret_cast<const bf16x8*>(bp);
        bf16x8 b1 = *reinterpret_cast<const bf16x8*>(bp + 32);
        #pragma unroll
        for (int tt = 0; tt < 2; tt++) {
            const unsigned short* ap = wbf + tap * 4096 + (size_t)(oc0 + tt * 16 + r15) * 64 + g * 8;
            bf16x8 a0 = *reinterpret_cast<const bf16x8*>(ap);
            bf16x8 a1 = *reinterpret_cast<const bf16x8*>(ap + 32);
            acc[tt] = __builtin_amdgcn_mfma_f32_16x16x32_bf16(a0, b0, acc[tt], 0, 0, 0);
            acc[tt] = __builtin_amdgcn_mfma_f32_16x16x32_bf16(a1, b1, acc[tt], 0, 0, 0);
        }
    }
    int n0 = y * 64 + x0;
    #pragma unroll
    for (int tt = 0; tt < 2; tt++) {
        #pragma unroll
        for (int r = 0; r < 4; r++)
            out[((size_t)b * 64 + oc0 + tt * 16 + g * 4 + r) * HW + n0 + r15] = acc[tt][r];
    }
}

extern "C" void kernel_launch(void* const* d_in, const int* in_sizes, int n_in,
                              void* d_out, int out_size, void* d_ws, size_t ws_size,
                              hipStream_t stream) {
    const float* x    = (const float*)d_in[0];
    const float* wqkv = (const float*)d_in[1];
    const float* wdw  = (const float*)d_in[2];
    const float* wprj = (const float*)d_in[3];
    char* ws = (char*)d_ws;
    float* qkv_raw       = (float*)(ws + 0);          // dead after dwconv
    float* qkv           = (float*)(ws + 12582912);   // dead after pack
    unsigned short* qT   = (unsigned short*)(ws + 25165824);
    unsigned short* kT   = (unsigned short*)(ws + 27262976);
    unsigned short* vn   = (unsigned short*)(ws + 29360128);
    float* psq           = (float*)(ws + 31457280);   // 32,768 B
    float* wk            = (float*)(ws + 31490048);   // 1,024 B
    float* rowsum_part   = (float*)(ws + 31491072);   // 524,288 B (8 partials)
    float* l2i           = (float*)(ws + 32015360);   // 65,536 B
    unsigned short* wbf  = (unsigned short*)(ws + 32080896);  // 73,728 B
    unsigned short* inP  = (unsigned short*)(ws + 32154624);  // 2,230,272 B -> ends 34,384,896

    int inP4 = (4 * PROWS * 64 * 2) / 16;  // 139392 float4
    k_init       <<<dim3(689),        256, 0, stream>>>((float4*)inP, inP4, wprj, wbf);
    k_conv1x1    <<<dim3(16, 24, 4),  256, 0, stream>>>(x, wqkv, qkv_raw);
    k_dwconv     <<<dim3(16, 192, 4), 256, 0, stream>>>(qkv_raw, wdw, qkv, psq);
    k_scales     <<<dim3(1),          256, 0, stream>>>(psq, wk);
    k_pack       <<<dim3(16, 3, 4),   256, 0, stream>>>(qkv, wk, qT, kT, vn);
    k_rowsum     <<<dim3(1024),       256, 0, stream>>>(qT, kT, rowsum_part);
    k_l2i        <<<dim3(64),         256, 0, stream>>>(rowsum_part, l2i);
    k_attn_fused <<<dim3(512),        512, 0, stream>>>(qT, kT, vn, l2i, inP);
    k_proj_mfma  <<<dim3(128, 4),     256, 0, stream>>>(inP, wbf, (float*)d_out);
}

// Round 18
// 111.228 us; speedup vs baseline: 1.1643x; 1.1643x over previous
//
#include <hip/hip_runtime.h>
#include <hip/hip_bf16.h>

typedef __attribute__((ext_vector_type(8))) short bf16x8;
typedef __attribute__((ext_vector_type(4))) float f32x4;
typedef __attribute__((ext_vector_type(8))) unsigned short ushort8;

#define HW 4096
#define NC 64
#define PROWS 4356  // 66*66 padded rows

static __device__ __forceinline__ unsigned short f2bf(float f) {
    unsigned int u = __float_as_uint(f);
    unsigned int r = (u + 0x7FFFu + ((u >> 16) & 1u)) >> 16;
    return (unsigned short)r;
}

// ---------------- init: zero inP + convert proj weights to bf16 [tap][oc][ic]
__global__ __launch_bounds__(256) void k_init(float4* __restrict__ p, int n4,
                                              const float* __restrict__ wp,
                                              unsigned short* __restrict__ wbf) {
    int bx = blockIdx.x;
    int t = threadIdx.x;
    if (bx < 545) {
        int i = bx * 256 + t;
        if (i < n4) p[i] = make_float4(0.f, 0.f, 0.f, 0.f);
    } else {
        int idx = (bx - 545) * 256 + t;  // 36864 total
        int tap = idx >> 12;
        int rem = idx & 4095;
        int oc = rem >> 6, ic = rem & 63;
        wbf[idx] = f2bf(wp[(oc * 64 + ic) * 9 + tap]);
    }
}

// ---------------- conv 1x1: qkv_raw[b][oc][n] = sum_ic w[oc][ic]*x[b][ic][n]
__global__ __launch_bounds__(256) void k_conv1x1(const float* __restrict__ x,
                                                 const float* __restrict__ wqkv,
                                                 float* __restrict__ out) {
    __shared__ float wl[512]; // 8 oc x 64 ic
    int nb = blockIdx.x, ocg = blockIdx.y, b = blockIdx.z;
    int t = threadIdx.x;
    for (int i = t; i < 512; i += 256) wl[i] = wqkv[ocg * 512 + i];
    __syncthreads();
    int n = nb * 256 + t;
    const float* xb = x + (size_t)b * NC * HW + n;
    float acc[8] = {0.f,0.f,0.f,0.f,0.f,0.f,0.f,0.f};
    for (int ic = 0; ic < 64; ic++) {
        float xv = xb[(size_t)ic * HW];
        #pragma unroll
        for (int o = 0; o < 8; o++) acc[o] += wl[o * 64 + ic] * xv;
    }
    float* ob = out + (size_t)b * 192 * HW + (size_t)(ocg * 8) * HW + n;
    #pragma unroll
    for (int o = 0; o < 8; o++) ob[(size_t)o * HW] = acc[o];
}

// ---------------- depthwise 3x3 SAME + per-channel partial sum of squares (q,k)
__global__ __launch_bounds__(256) void k_dwconv(const float* __restrict__ in,
                                                const float* __restrict__ wdw,
                                                float* __restrict__ out,
                                                float* __restrict__ psq) {
    int yg = blockIdx.x, ch = blockIdx.y, b = blockIdx.z;
    int t = threadIdx.x;
    int y = yg * 4 + (t >> 6), xx = t & 63;
    const float* ib = in + ((size_t)b * 192 + ch) * HW;
    const float* wp = wdw + ch * 9;
    float s = 0.f;
    #pragma unroll
    for (int dy = 0; dy < 3; dy++) {
        int yy = y + dy - 1;
        if (yy < 0 || yy > 63) continue;
        const float* r = ib + yy * 64;
        float v0 = (xx > 0) ? r[xx - 1] : 0.f;
        float v1 = r[xx];
        float v2 = (xx < 63) ? r[xx + 1] : 0.f;
        const float* wr = wp + dy * 3;
        s += wr[0] * v0 + wr[1] * v1 + wr[2] * v2;
    }
    out[((size_t)b * 192 + ch) * HW + y * 64 + xx] = s;
    if (ch < 128) {
        float sq = s * s;
        #pragma unroll
        for (int m = 1; m < 64; m <<= 1) sq += __shfl_xor(sq, m);
        __shared__ float red[4];
        if ((t & 63) == 0) red[t >> 6] = sq;
        __syncthreads();
        if (t == 0)
            psq[((size_t)b * 128 + ch) * 16 + yg] = red[0] + red[1] + red[2] + red[3];
    }
}

// ---------------- combined K-side scale: wk[b][c] = log2e / (max(|q_c|,eps)*max(|k_c|,eps))
__global__ __launch_bounds__(256) void k_scales(const float* __restrict__ psq,
                                                float* __restrict__ wk) {
    int i = threadIdx.x;  // 256 = 4 b x 64 c
    int b = i >> 6, c = i & 63;
    const float* pq = psq + ((size_t)b * 128 + c) * 16;
    const float* pk = psq + ((size_t)b * 128 + 64 + c) * 16;
    float sq = 0.f, sk = 0.f;
    #pragma unroll
    for (int j = 0; j < 16; j++) { sq += pq[j]; sk += pk[j]; }
    float nq = fmaxf(sqrtf(sq), 1e-12f);
    float nk = fmaxf(sqrtf(sk), 1e-12f);
    wk[i] = 1.4426950408889634f / (nq * nk);
}

// ---------------- pack: qT raw bf16 [b][n][c]; kT scaled by wk; vn [b][c][n]
__global__ __launch_bounds__(256) void k_pack(const float* __restrict__ qkv,
                                              const float* __restrict__ wk,
                                              unsigned short* __restrict__ qT,
                                              unsigned short* __restrict__ kT,
                                              unsigned short* __restrict__ vn) {
    int nb = blockIdx.x, sel = blockIdx.y, b = blockIdx.z;
    int n = nb * 256 + threadIdx.x;
    if (sel == 2) {
        const float* src = qkv + ((size_t)b * 192 + 128) * HW + n;
        unsigned short* dst = vn + (size_t)b * NC * HW + n;
        for (int c = 0; c < 64; c++) dst[(size_t)c * HW] = f2bf(src[(size_t)c * HW]);
    } else if (sel == 0) {
        const float* src = qkv + (size_t)b * 192 * HW + n;
        unsigned short* dst = qT + ((size_t)b * HW + n) * NC;
        for (int c0 = 0; c0 < 64; c0 += 8) {
            ushort8 pk;
            #pragma unroll
            for (int j = 0; j < 8; j++) pk[j] = f2bf(src[(size_t)(c0 + j) * HW]);
            *reinterpret_cast<ushort8*>(dst + c0) = pk;
        }
    } else {
        const float* src = qkv + ((size_t)b * 192 + 64) * HW + n;
        const float* wv = wk + b * 64;
        unsigned short* dst = kT + ((size_t)b * HW + n) * NC;
        for (int c0 = 0; c0 < 64; c0 += 8) {
            ushort8 pk;
            #pragma unroll
            for (int j = 0; j < 8; j++)
                pk[j] = f2bf(src[(size_t)(c0 + j) * HW] * wv[c0 + j]);
            *reinterpret_cast<ushort8*>(dst + c0) = pk;
        }
    }
}

// ---------------- pass 1: D[m] = sum_n exp2(s'[m,n]); K-tile double-buffered LDS.
// 1D grid (1024) with XCD-aware decode: batch pinned to an XCD pair -> L2-resident.
__global__ __launch_bounds__(256) void k_rowsum(const unsigned short* __restrict__ qT,
                                                const unsigned short* __restrict__ kT,
                                                float* __restrict__ part) {
    __shared__ __align__(16) unsigned short klds[2][64 * 72];
    int i = blockIdx.x;
    int b = (i >> 1) & 3;
    int mblk = (i >> 3) & 31;
    int ns = ((i >> 8) & 3) * 2 + (i & 1);
    int t = threadIdx.x;
    int w = t >> 6, lane = t & 63, g = lane >> 4, r15 = lane & 15;
    const unsigned short* qb = qT + (size_t)b * HW * NC;
    const unsigned short* kb = kT + (size_t)b * HW * NC;
    int m0 = mblk * 128 + w * 16;
    const unsigned short* qp0 = qb + (size_t)(m0 + r15) * NC + g * 8;
    const unsigned short* qp1 = qb + (size_t)(m0 + 64 + r15) * NC + g * 8;
    bf16x8 a0 = *reinterpret_cast<const bf16x8*>(qp0);
    bf16x8 a1 = *reinterpret_cast<const bf16x8*>(qp0 + 32);
    bf16x8 a2 = *reinterpret_cast<const bf16x8*>(qp1);
    bf16x8 a3 = *reinterpret_cast<const bf16x8*>(qp1 + 32);
    float sa[4] = {0.f, 0.f, 0.f, 0.f};
    float sb[4] = {0.f, 0.f, 0.f, 0.f};
    int nbase = ns * 512;
    int nl = t >> 2, seg = t & 3;
    {
        const unsigned short* sp = kb + (size_t)(nbase + nl) * NC + seg * 16;
        *reinterpret_cast<ushort8*>(&klds[0][nl * 72 + seg * 16]) = *reinterpret_cast<const ushort8*>(sp);
        *reinterpret_cast<ushort8*>(&klds[0][nl * 72 + seg * 16 + 8]) = *reinterpret_cast<const ushort8*>(sp + 8);
    }
    __syncthreads();
    int cur = 0;
    for (int it = 0; it < 8; it++) {
        ushort8 r0, r1;
        bool hasnext = it < 7;
        if (hasnext) {
            const unsigned short* sp = kb + (size_t)(nbase + (it + 1) * 64 + nl) * NC + seg * 16;
            r0 = *reinterpret_cast<const ushort8*>(sp);
            r1 = *reinterpret_cast<const ushort8*>(sp + 8);
        }
        #pragma unroll
        for (int tt = 0; tt < 4; tt++) {
            const unsigned short* kp = &klds[cur][(tt * 16 + r15) * 72 + g * 8];
            bf16x8 b0 = *reinterpret_cast<const bf16x8*>(kp);
            bf16x8 b1 = *reinterpret_cast<const bf16x8*>(kp + 32);
            f32x4 d0 = {0.f, 0.f, 0.f, 0.f};
            f32x4 d1 = {0.f, 0.f, 0.f, 0.f};
            d0 = __builtin_amdgcn_mfma_f32_16x16x32_bf16(a0, b0, d0, 0, 0, 0);
            d1 = __builtin_amdgcn_mfma_f32_16x16x32_bf16(a2, b0, d1, 0, 0, 0);
            d0 = __builtin_amdgcn_mfma_f32_16x16x32_bf16(a1, b1, d0, 0, 0, 0);
            d1 = __builtin_amdgcn_mfma_f32_16x16x32_bf16(a3, b1, d1, 0, 0, 0);
            #pragma unroll
            for (int r = 0; r < 4; r++) {
                sa[r] += __builtin_amdgcn_exp2f(d0[r]);
                sb[r] += __builtin_amdgcn_exp2f(d1[r]);
            }
        }
        if (hasnext) {
            *reinterpret_cast<ushort8*>(&klds[cur ^ 1][nl * 72 + seg * 16]) = r0;
            *reinterpret_cast<ushort8*>(&klds[cur ^ 1][nl * 72 + seg * 16 + 8]) = r1;
            cur ^= 1;
        }
        __syncthreads();
    }
    #pragma unroll
    for (int off = 1; off < 16; off <<= 1) {
        #pragma unroll
        for (int r = 0; r < 4; r++) {
            sa[r] += __shfl_xor(sa[r], off);
            sb[r] += __shfl_xor(sb[r], off);
        }
    }
    if (r15 == 0) {
        size_t base = ((size_t)ns * 4 + b) * HW;
        f32x4 va = {sa[0], sa[1], sa[2], sa[3]};
        f32x4 vb = {sb[0], sb[1], sb[2], sb[3]};
        *reinterpret_cast<f32x4*>(&part[base + m0 + g * 4]) = va;
        *reinterpret_cast<f32x4*>(&part[base + m0 + 64 + g * 4]) = vb;
    }
}

// ---------------- l2i[m] = -log2(D[m]) (folds softmax denom into MFMA C-init)
__global__ __launch_bounds__(256) void k_l2i(const float* __restrict__ part,
                                             float* __restrict__ l2i) {
    int i = blockIdx.x * 256 + threadIdx.x;  // 16384 = 4*HW
    float s = 0.f;
    #pragma unroll
    for (int ns = 0; ns < 8; ns++) s += part[i + ns * 4 * HW];
    l2i[i] = -log2f(s);
}

// ---------------- fused pass 2 (barrier-free, 64-col blocks, R15-proven body)
// + s_setprio(1) around MFMA clusters (T5: helps independent-wave attn kernels).
__global__ __launch_bounds__(512, 2) void k_attn_fused(const unsigned short* __restrict__ qT,
                                                       const unsigned short* __restrict__ kT,
                                                       const unsigned short* __restrict__ vn,
                                                       const float* __restrict__ l2i,
                                                       unsigned short* __restrict__ inP) {
    __shared__ float red[8][64][8];  // 16 KB epilogue reduce
    int nb = blockIdx.x, b = blockIdx.y;
    int t = threadIdx.x;
    int w = t >> 6, lane = t & 63, g = lane >> 4, r15 = lane & 15;
    int n0 = nb * 64;
    const unsigned short* qb = qT + (size_t)b * HW * NC;
    const unsigned short* kbp = kT + (size_t)b * HW * NC;
    const unsigned short* vb = vn + (size_t)b * NC * HW;
    const float* rib = l2i + (size_t)b * HW;
    // K-fragments resident in registers (all 8 waves load the same -> L1 hits)
    bf16x8 kf0[4], kf1[4];
    #pragma unroll
    for (int tt = 0; tt < 4; tt++) {
        const unsigned short* kp = kbp + (size_t)(n0 + tt * 16 + r15) * NC + g * 8;
        kf0[tt] = *reinterpret_cast<const bf16x8*>(kp);
        kf1[tt] = *reinterpret_cast<const bf16x8*>(kp + 32);
    }
    f32x4 acc[4][4];
    #pragma unroll
    for (int ct = 0; ct < 4; ct++)
        #pragma unroll
        for (int tt = 0; tt < 4; tt++) acc[ct][tt] = f32x4{0.f, 0.f, 0.f, 0.f};
    int mw = w * 32;
    // permuted Q row: S-tile ts loads m = base + (r15>>2)*8 + ts*4 + (r15&3)
    int qrow = (r15 >> 2) * 8 + (r15 & 3);
    const unsigned short* qrp = qb + (size_t)(mw + qrow) * NC;
    bf16x8 qa[2][2];
    #pragma unroll
    for (int ts = 0; ts < 2; ts++) {
        qa[ts][0] = *reinterpret_cast<const bf16x8*>(qrp + ts * 4 * NC + g * 8);
        qa[ts][1] = *reinterpret_cast<const bf16x8*>(qrp + ts * 4 * NC + 32 + g * 8);
    }
    f32x4 iv0 = *reinterpret_cast<const f32x4*>(rib + mw + g * 8);
    f32x4 iv1 = *reinterpret_cast<const f32x4*>(rib + mw + g * 8 + 4);
    for (int it = 0; it < 16; it++) {
        int mb = it * 256;
        // V fragments for current iter (consumed ~200 cyc later in PV)
        bf16x8 va[4];
        #pragma unroll
        for (int ct = 0; ct < 4; ct++)
            va[ct] = *reinterpret_cast<const bf16x8*>(vb + (size_t)(ct * 16 + r15) * HW + mb + mw + g * 8);
        // prefetch next-iter Q and l2i (latency hidden under S+PV compute)
        int adv = (it < 15) ? 256 : 0;
        const unsigned short* qrn = qrp + (size_t)adv * NC;
        bf16x8 qn[2][2];
        #pragma unroll
        for (int ts = 0; ts < 2; ts++) {
            qn[ts][0] = *reinterpret_cast<const bf16x8*>(qrn + ts * 4 * NC + g * 8);
            qn[ts][1] = *reinterpret_cast<const bf16x8*>(qrn + ts * 4 * NC + 32 + g * 8);
        }
        f32x4 ivn0 = *reinterpret_cast<const f32x4*>(rib + mb + adv + mw + g * 8);
        f32x4 ivn1 = *reinterpret_cast<const f32x4*>(rib + mb + adv + mw + g * 8 + 4);
        // S phase: C-init = l2i -> P = exp2(s' + l2i); lane-local D rows map to m = g*8 + ts*4 + r
        bf16x8 pb[4];
        #pragma unroll
        for (int tt = 0; tt < 4; tt++) {
            __builtin_amdgcn_s_setprio(1);
            f32x4 d0 = __builtin_amdgcn_mfma_f32_16x16x32_bf16(qa[0][0], kf0[tt], iv0, 0, 0, 0);
            d0 = __builtin_amdgcn_mfma_f32_16x16x32_bf16(qa[0][1], kf1[tt], d0, 0, 0, 0);
            f32x4 d1 = __builtin_amdgcn_mfma_f32_16x16x32_bf16(qa[1][0], kf0[tt], iv1, 0, 0, 0);
            d1 = __builtin_amdgcn_mfma_f32_16x16x32_bf16(qa[1][1], kf1[tt], d1, 0, 0, 0);
            __builtin_amdgcn_s_setprio(0);
            float e0 = exp2f(d0[0]);
            float e1 = exp2f(d0[1]);
            float e2 = exp2f(d0[2]);
            float e3 = exp2f(d0[3]);
            float f0 = exp2f(d1[0]);
            float f1 = exp2f(d1[1]);
            float f2 = exp2f(d1[2]);
            float f3 = exp2f(d1[3]);
            unsigned int p0, p1, p2, p3;
            asm("v_cvt_pk_bf16_f32 %0, %1, %2" : "=v"(p0) : "v"(e0), "v"(e1));
            asm("v_cvt_pk_bf16_f32 %0, %1, %2" : "=v"(p1) : "v"(e2), "v"(e3));
            asm("v_cvt_pk_bf16_f32 %0, %1, %2" : "=v"(p2) : "v"(f0), "v"(f1));
            asm("v_cvt_pk_bf16_f32 %0, %1, %2" : "=v"(p3) : "v"(f2), "v"(f3));
            union { unsigned int u[4]; bf16x8 v; } pu;
            pu.u[0] = p0; pu.u[1] = p1; pu.u[2] = p2; pu.u[3] = p3;
            pb[tt] = pu.v;
        }
        // PV phase: full-rate 16x16x32, k = the wave's 32-m slice
        __builtin_amdgcn_s_setprio(1);
        #pragma unroll
        for (int ct = 0; ct < 4; ct++)
            #pragma unroll
            for (int tt = 0; tt < 4; tt++)
                acc[ct][tt] = __builtin_amdgcn_mfma_f32_16x16x32_bf16(va[ct], pb[tt], acc[ct][tt], 0, 0, 0);
        __builtin_amdgcn_s_setprio(0);
        #pragma unroll
        for (int ts = 0; ts < 2; ts++) { qa[ts][0] = qn[ts][0]; qa[ts][1] = qn[ts][1]; }
        iv0 = ivn0; iv1 = ivn1;
        qrp += (size_t)adv * NC;
    }
    // cross-wave reduce (8 partial sums) + bf16 store into padded transposed inP
    #pragma unroll
    for (int ph = 0; ph < 8; ph++) {
        int ct = ph >> 1, th = ph & 1;
        *reinterpret_cast<f32x4*>(&red[w][lane][0]) = acc[ct][th * 2];
        *reinterpret_cast<f32x4*>(&red[w][lane][4]) = acc[ct][th * 2 + 1];
        __syncthreads();
        int lr = t >> 3, kk = t & 7;
        float s = 0.f;
        #pragma unroll
        for (int ww = 0; ww < 8; ww++) s += red[ww][lr][kk];
        int c = ct * 16 + ((lr >> 4) << 2) + (kk & 3);
        int nn = n0 + (th * 2 + (kk >> 2)) * 16 + (lr & 15);
        int y = nn >> 6, xx = nn & 63;
        inP[((size_t)b * PROWS + (size_t)(y + 1) * 66 + 1 + xx) * 64 + c] = f2bf(s);
        __syncthreads();
    }
}

// ---------------- proj conv 3x3 via MFMA: 9 shifted GEMMs
__global__ __launch_bounds__(256) void k_proj_mfma(const unsigned short* __restrict__ inP,
                                                   const unsigned short* __restrict__ wbf,
                                                   float* __restrict__ out) {
    int nb = blockIdx.x, b = blockIdx.y;
    int t = threadIdx.x;
    int w = t >> 6, lane = t & 63, g = lane >> 4, r15 = lane & 15;
    int y = nb >> 1;
    int x0 = (nb & 1) * 32 + (w & 1) * 16;
    int oc0 = (w >> 1) * 32;
    const unsigned short* base = inP + (size_t)b * PROWS * 64;
    f32x4 acc[2] = {{0.f,0.f,0.f,0.f},{0.f,0.f,0.f,0.f}};
    #pragma unroll
    for (int tap = 0; tap < 9; tap++) {
        int dy = tap / 3, dx = tap % 3;
        int p = (y + dy) * 66 + x0 + dx + r15;
        const unsigned short* bp = base + (size_t)p * 64 + g * 8;
        bf16x8 b0 = *reinterpret_cast<const bf16x8*>(bp);
        bf16x8 b1 = *reinterpret_cast<const bf16x8*>(bp + 32);
        #pragma unroll
        for (int tt = 0; tt < 2; tt++) {
            const unsigned short* ap = wbf + tap * 4096 + (size_t)(oc0 + tt * 16 + r15) * 64 + g * 8;
            bf16x8 a0 = *reinterpret_cast<const bf16x8*>(ap);
            bf16x8 a1 = *reinterpret_cast<const bf16x8*>(ap + 32);
            acc[tt] = __builtin_amdgcn_mfma_f32_16x16x32_bf16(a0, b0, acc[tt], 0, 0, 0);
            acc[tt] = __builtin_amdgcn_mfma_f32_16x16x32_bf16(a1, b1, acc[tt], 0, 0, 0);
        }
    }
    int n0 = y * 64 + x0;
    #pragma unroll
    for (int tt = 0; tt < 2; tt++) {
        #pragma unroll
        for (int r = 0; r < 4; r++)
            out[((size_t)b * 64 + oc0 + tt * 16 + g * 4 + r) * HW + n0 + r15] = acc[tt][r];
    }
}

extern "C" void kernel_launch(void* const* d_in, const int* in_sizes, int n_in,
                              void* d_out, int out_size, void* d_ws, size_t ws_size,
                              hipStream_t stream) {
    const float* x    = (const float*)d_in[0];
    const float* wqkv = (const float*)d_in[1];
    const float* wdw  = (const float*)d_in[2];
    const float* wprj = (const float*)d_in[3];
    char* ws = (char*)d_ws;
    float* qkv_raw       = (float*)(ws + 0);          // dead after dwconv
    float* qkv           = (float*)(ws + 12582912);   // dead after pack
    unsigned short* qT   = (unsigned short*)(ws + 25165824);
    unsigned short* kT   = (unsigned short*)(ws + 27262976);
    unsigned short* vn   = (unsigned short*)(ws + 29360128);
    float* psq           = (float*)(ws + 31457280);   // 32,768 B
    float* wk            = (float*)(ws + 31490048);   // 1,024 B
    float* rowsum_part   = (float*)(ws + 31491072);   // 524,288 B (8 partials)
    float* l2i           = (float*)(ws + 32015360);   // 65,536 B
    unsigned short* wbf  = (unsigned short*)(ws + 32080896);  // 73,728 B
    unsigned short* inP  = (unsigned short*)(ws + 32154624);  // 2,230,272 B -> ends 34,384,896

    int inP4 = (4 * PROWS * 64 * 2) / 16;  // 139392 float4
    k_init       <<<dim3(689),        256, 0, stream>>>((float4*)inP, inP4, wprj, wbf);
    k_conv1x1    <<<dim3(16, 24, 4),  256, 0, stream>>>(x, wqkv, qkv_raw);
    k_dwconv     <<<dim3(16, 192, 4), 256, 0, stream>>>(qkv_raw, wdw, qkv, psq);
    k_scales     <<<dim3(1),          256, 0, stream>>>(psq, wk);
    k_pack       <<<dim3(16, 3, 4),   256, 0, stream>>>(qkv, wk, qT, kT, vn);
    k_rowsum     <<<dim3(1024),       256, 0, stream>>>(qT, kT, rowsum_part);
    k_l2i        <<<dim3(64),         256, 0, stream>>>(rowsum_part, l2i);
    k_attn_fused <<<dim3(64, 4),      512, 0, stream>>>(qT, kT, vn, l2i, inP);
    k_proj_mfma  <<<dim3(128, 4),     256, 0, stream>>>(inP, wbf, (float*)d_out);
}

// Round 19
// 110.477 us; speedup vs baseline: 1.1722x; 1.0068x over previous
//
#include <hip/hip_runtime.h>
#include <hip/hip_bf16.h>

typedef __attribute__((ext_vector_type(8))) short bf16x8;
typedef __attribute__((ext_vector_type(4))) float f32x4;
typedef __attribute__((ext_vector_type(8))) unsigned short ushort8;

#define HW 4096
#define NC 64
#define PROWS 4356  // 66*66 padded rows

static __device__ __forceinline__ unsigned short f2bf(float f) {
    unsigned int u = __float_as_uint(f);
    unsigned int r = (u + 0x7FFFu + ((u >> 16) & 1u)) >> 16;
    return (unsigned short)r;
}

// ---------------- init: zero inP + convert proj weights to bf16 [tap][oc][ic]
__global__ __launch_bounds__(256) void k_init(float4* __restrict__ p, int n4,
                                              const float* __restrict__ wp,
                                              unsigned short* __restrict__ wbf) {
    int bx = blockIdx.x;
    int t = threadIdx.x;
    if (bx < 545) {
        int i = bx * 256 + t;
        if (i < n4) p[i] = make_float4(0.f, 0.f, 0.f, 0.f);
    } else {
        int idx = (bx - 545) * 256 + t;  // 36864 total
        int tap = idx >> 12;
        int rem = idx & 4095;
        int oc = rem >> 6, ic = rem & 63;
        wbf[idx] = f2bf(wp[(oc * 64 + ic) * 9 + tap]);
    }
}

// ---------------- conv 1x1: qkv_raw[b][oc][n] = sum_ic w[oc][ic]*x[b][ic][n]
__global__ __launch_bounds__(256) void k_conv1x1(const float* __restrict__ x,
                                                 const float* __restrict__ wqkv,
                                                 float* __restrict__ out) {
    __shared__ float wl[512]; // 8 oc x 64 ic
    int nb = blockIdx.x, ocg = blockIdx.y, b = blockIdx.z;
    int t = threadIdx.x;
    for (int i = t; i < 512; i += 256) wl[i] = wqkv[ocg * 512 + i];
    __syncthreads();
    int n = nb * 256 + t;
    const float* xb = x + (size_t)b * NC * HW + n;
    float acc[8] = {0.f,0.f,0.f,0.f,0.f,0.f,0.f,0.f};
    for (int ic = 0; ic < 64; ic++) {
        float xv = xb[(size_t)ic * HW];
        #pragma unroll
        for (int o = 0; o < 8; o++) acc[o] += wl[o * 64 + ic] * xv;
    }
    float* ob = out + (size_t)b * 192 * HW + (size_t)(ocg * 8) * HW + n;
    #pragma unroll
    for (int o = 0; o < 8; o++) ob[(size_t)o * HW] = acc[o];
}

// ---------------- depthwise 3x3 SAME + per-channel partial sum of squares (q,k)
__global__ __launch_bounds__(256) void k_dwconv(const float* __restrict__ in,
                                                const float* __restrict__ wdw,
                                                float* __restrict__ out,
                                                float* __restrict__ psq) {
    int yg = blockIdx.x, ch = blockIdx.y, b = blockIdx.z;
    int t = threadIdx.x;
    int y = yg * 4 + (t >> 6), xx = t & 63;
    const float* ib = in + ((size_t)b * 192 + ch) * HW;
    const float* wp = wdw + ch * 9;
    float s = 0.f;
    #pragma unroll
    for (int dy = 0; dy < 3; dy++) {
        int yy = y + dy - 1;
        if (yy < 0 || yy > 63) continue;
        const float* r = ib + yy * 64;
        float v0 = (xx > 0) ? r[xx - 1] : 0.f;
        float v1 = r[xx];
        float v2 = (xx < 63) ? r[xx + 1] : 0.f;
        const float* wr = wp + dy * 3;
        s += wr[0] * v0 + wr[1] * v1 + wr[2] * v2;
    }
    out[((size_t)b * 192 + ch) * HW + y * 64 + xx] = s;
    if (ch < 128) {
        float sq = s * s;
        #pragma unroll
        for (int m = 1; m < 64; m <<= 1) sq += __shfl_xor(sq, m);
        __shared__ float red[4];
        if ((t & 63) == 0) red[t >> 6] = sq;
        __syncthreads();
        if (t == 0)
            psq[((size_t)b * 128 + ch) * 16 + yg] = red[0] + red[1] + red[2] + red[3];
    }
}

// ---------------- combined K-side scale: wk[b][c] = log2e / (max(|q_c|,eps)*max(|k_c|,eps))
__global__ __launch_bounds__(256) void k_scales(const float* __restrict__ psq,
                                                float* __restrict__ wk) {
    int i = threadIdx.x;  // 256 = 4 b x 64 c
    int b = i >> 6, c = i & 63;
    const float* pq = psq + ((size_t)b * 128 + c) * 16;
    const float* pk = psq + ((size_t)b * 128 + 64 + c) * 16;
    float sq = 0.f, sk = 0.f;
    #pragma unroll
    for (int j = 0; j < 16; j++) { sq += pq[j]; sk += pk[j]; }
    float nq = fmaxf(sqrtf(sq), 1e-12f);
    float nk = fmaxf(sqrtf(sk), 1e-12f);
    wk[i] = 1.4426950408889634f / (nq * nk);
}

// ---------------- pack: qT raw bf16 [b][n][c]; kT scaled by wk; vn [b][c][n]
__global__ __launch_bounds__(256) void k_pack(const float* __restrict__ qkv,
                                              const float* __restrict__ wk,
                                              unsigned short* __restrict__ qT,
                                              unsigned short* __restrict__ kT,
                                              unsigned short* __restrict__ vn) {
    int nb = blockIdx.x, sel = blockIdx.y, b = blockIdx.z;
    int n = nb * 256 + threadIdx.x;
    if (sel == 2) {
        const float* src = qkv + ((size_t)b * 192 + 128) * HW + n;
        unsigned short* dst = vn + (size_t)b * NC * HW + n;
        for (int c = 0; c < 64; c++) dst[(size_t)c * HW] = f2bf(src[(size_t)c * HW]);
    } else if (sel == 0) {
        const float* src = qkv + (size_t)b * 192 * HW + n;
        unsigned short* dst = qT + ((size_t)b * HW + n) * NC;
        for (int c0 = 0; c0 < 64; c0 += 8) {
            ushort8 pk;
            #pragma unroll
            for (int j = 0; j < 8; j++) pk[j] = f2bf(src[(size_t)(c0 + j) * HW]);
            *reinterpret_cast<ushort8*>(dst + c0) = pk;
        }
    } else {
        const float* src = qkv + ((size_t)b * 192 + 64) * HW + n;
        const float* wv = wk + b * 64;
        unsigned short* dst = kT + ((size_t)b * HW + n) * NC;
        for (int c0 = 0; c0 < 64; c0 += 8) {
            ushort8 pk;
            #pragma unroll
            for (int j = 0; j < 8; j++)
                pk[j] = f2bf(src[(size_t)(c0 + j) * HW] * wv[c0 + j]);
            *reinterpret_cast<ushort8*>(dst + c0) = pk;
        }
    }
}

// ---------------- pass 1: D[m] = sum_n exp2(s'[m,n]); K-tile double-buffered LDS.
// 1D grid (1024) with XCD-aware decode: batch pinned to an XCD pair -> L2-resident.
__global__ __launch_bounds__(256) void k_rowsum(const unsigned short* __restrict__ qT,
                                                const unsigned short* __restrict__ kT,
                                                float* __restrict__ part) {
    __shared__ __align__(16) unsigned short klds[2][64 * 72];
    int i = blockIdx.x;
    int b = (i >> 1) & 3;
    int mblk = (i >> 3) & 31;
    int ns = ((i >> 8) & 3) * 2 + (i & 1);
    int t = threadIdx.x;
    int w = t >> 6, lane = t & 63, g = lane >> 4, r15 = lane & 15;
    const unsigned short* qb = qT + (size_t)b * HW * NC;
    const unsigned short* kb = kT + (size_t)b * HW * NC;
    int m0 = mblk * 128 + w * 16;
    const unsigned short* qp0 = qb + (size_t)(m0 + r15) * NC + g * 8;
    const unsigned short* qp1 = qb + (size_t)(m0 + 64 + r15) * NC + g * 8;
    bf16x8 a0 = *reinterpret_cast<const bf16x8*>(qp0);
    bf16x8 a1 = *reinterpret_cast<const bf16x8*>(qp0 + 32);
    bf16x8 a2 = *reinterpret_cast<const bf16x8*>(qp1);
    bf16x8 a3 = *reinterpret_cast<const bf16x8*>(qp1 + 32);
    float sa[4] = {0.f, 0.f, 0.f, 0.f};
    float sb[4] = {0.f, 0.f, 0.f, 0.f};
    int nbase = ns * 512;
    int nl = t >> 2, seg = t & 3;
    {
        const unsigned short* sp = kb + (size_t)(nbase + nl) * NC + seg * 16;
        *reinterpret_cast<ushort8*>(&klds[0][nl * 72 + seg * 16]) = *reinterpret_cast<const ushort8*>(sp);
        *reinterpret_cast<ushort8*>(&klds[0][nl * 72 + seg * 16 + 8]) = *reinterpret_cast<const ushort8*>(sp + 8);
    }
    __syncthreads();
    int cur = 0;
    for (int it = 0; it < 8; it++) {
        ushort8 r0, r1;
        bool hasnext = it < 7;
        if (hasnext) {
            const unsigned short* sp = kb + (size_t)(nbase + (it + 1) * 64 + nl) * NC + seg * 16;
            r0 = *reinterpret_cast<const ushort8*>(sp);
            r1 = *reinterpret_cast<const ushort8*>(sp + 8);
        }
        #pragma unroll
        for (int tt = 0; tt < 4; tt++) {
            const unsigned short* kp = &klds[cur][(tt * 16 + r15) * 72 + g * 8];
            bf16x8 b0 = *reinterpret_cast<const bf16x8*>(kp);
            bf16x8 b1 = *reinterpret_cast<const bf16x8*>(kp + 32);
            f32x4 d0 = {0.f, 0.f, 0.f, 0.f};
            f32x4 d1 = {0.f, 0.f, 0.f, 0.f};
            d0 = __builtin_amdgcn_mfma_f32_16x16x32_bf16(a0, b0, d0, 0, 0, 0);
            d1 = __builtin_amdgcn_mfma_f32_16x16x32_bf16(a2, b0, d1, 0, 0, 0);
            d0 = __builtin_amdgcn_mfma_f32_16x16x32_bf16(a1, b1, d0, 0, 0, 0);
            d1 = __builtin_amdgcn_mfma_f32_16x16x32_bf16(a3, b1, d1, 0, 0, 0);
            #pragma unroll
            for (int r = 0; r < 4; r++) {
                sa[r] += __builtin_amdgcn_exp2f(d0[r]);
                sb[r] += __builtin_amdgcn_exp2f(d1[r]);
            }
        }
        if (hasnext) {
            *reinterpret_cast<ushort8*>(&klds[cur ^ 1][nl * 72 + seg * 16]) = r0;
            *reinterpret_cast<ushort8*>(&klds[cur ^ 1][nl * 72 + seg * 16 + 8]) = r1;
            cur ^= 1;
        }
        __syncthreads();
    }
    #pragma unroll
    for (int off = 1; off < 16; off <<= 1) {
        #pragma unroll
        for (int r = 0; r < 4; r++) {
            sa[r] += __shfl_xor(sa[r], off);
            sb[r] += __shfl_xor(sb[r], off);
        }
    }
    if (r15 == 0) {
        size_t base = ((size_t)ns * 4 + b) * HW;
        f32x4 va = {sa[0], sa[1], sa[2], sa[3]};
        f32x4 vb = {sb[0], sb[1], sb[2], sb[3]};
        *reinterpret_cast<f32x4*>(&part[base + m0 + g * 4]) = va;
        *reinterpret_cast<f32x4*>(&part[base + m0 + 64 + g * 4]) = vb;
    }
}

// ---------------- l2i[m] = -log2(D[m]) (folds softmax denom into MFMA C-init)
__global__ __launch_bounds__(256) void k_l2i(const float* __restrict__ part,
                                             float* __restrict__ l2i) {
    int i = blockIdx.x * 256 + threadIdx.x;  // 16384 = 4*HW
    float s = 0.f;
    #pragma unroll
    for (int ns = 0; ns < 8; ns++) s += part[i + ns * 4 * HW];
    l2i[i] = -log2f(s);
}

// ---------------- fused pass 2 (barrier-free, 64-col blocks, R10/R15-proven body):
// each of 8 waves owns a 32-m slice per 256-m iter; permuted Q-row load makes the
// S-MFMA output the PV B-fragment; P = exp2(s' + l2i[m]) via MFMA C-init.
// launch_bounds(512,2): VGPR cap 256 -> ~84 VGPR, no spill.
__global__ __launch_bounds__(512, 2) void k_attn_fused(const unsigned short* __restrict__ qT,
                                                       const unsigned short* __restrict__ kT,
                                                       const unsigned short* __restrict__ vn,
                                                       const float* __restrict__ l2i,
                                                       unsigned short* __restrict__ inP) {
    __shared__ float red[8][64][8];  // 16 KB epilogue reduce
    int nb = blockIdx.x, b = blockIdx.y;
    int t = threadIdx.x;
    int w = t >> 6, lane = t & 63, g = lane >> 4, r15 = lane & 15;
    int n0 = nb * 64;
    const unsigned short* qb = qT + (size_t)b * HW * NC;
    const unsigned short* kbp = kT + (size_t)b * HW * NC;
    const unsigned short* vb = vn + (size_t)b * NC * HW;
    const float* rib = l2i + (size_t)b * HW;
    // K-fragments resident in registers (all 8 waves load the same -> L1 hits)
    bf16x8 kf0[4], kf1[4];
    #pragma unroll
    for (int tt = 0; tt < 4; tt++) {
        const unsigned short* kp = kbp + (size_t)(n0 + tt * 16 + r15) * NC + g * 8;
        kf0[tt] = *reinterpret_cast<const bf16x8*>(kp);
        kf1[tt] = *reinterpret_cast<const bf16x8*>(kp + 32);
    }
    f32x4 acc[4][4];
    #pragma unroll
    for (int ct = 0; ct < 4; ct++)
        #pragma unroll
        for (int tt = 0; tt < 4; tt++) acc[ct][tt] = f32x4{0.f, 0.f, 0.f, 0.f};
    int mw = w * 32;
    // permuted Q row: S-tile ts loads m = base + (r15>>2)*8 + ts*4 + (r15&3)
    int qrow = (r15 >> 2) * 8 + (r15 & 3);
    const unsigned short* qrp = qb + (size_t)(mw + qrow) * NC;
    bf16x8 qa[2][2];
    #pragma unroll
    for (int ts = 0; ts < 2; ts++) {
        qa[ts][0] = *reinterpret_cast<const bf16x8*>(qrp + ts * 4 * NC + g * 8);
        qa[ts][1] = *reinterpret_cast<const bf16x8*>(qrp + ts * 4 * NC + 32 + g * 8);
    }
    f32x4 iv0 = *reinterpret_cast<const f32x4*>(rib + mw + g * 8);
    f32x4 iv1 = *reinterpret_cast<const f32x4*>(rib + mw + g * 8 + 4);
    for (int it = 0; it < 16; it++) {
        int mb = it * 256;
        // V fragments for current iter (consumed ~200 cyc later in PV)
        bf16x8 va[4];
        #pragma unroll
        for (int ct = 0; ct < 4; ct++)
            va[ct] = *reinterpret_cast<const bf16x8*>(vb + (size_t)(ct * 16 + r15) * HW + mb + mw + g * 8);
        // prefetch next-iter Q and l2i (latency hidden under S+PV compute)
        int adv = (it < 15) ? 256 : 0;
        const unsigned short* qrn = qrp + (size_t)adv * NC;
        bf16x8 qn[2][2];
        #pragma unroll
        for (int ts = 0; ts < 2; ts++) {
            qn[ts][0] = *reinterpret_cast<const bf16x8*>(qrn + ts * 4 * NC + g * 8);
            qn[ts][1] = *reinterpret_cast<const bf16x8*>(qrn + ts * 4 * NC + 32 + g * 8);
        }
        f32x4 ivn0 = *reinterpret_cast<const f32x4*>(rib + mb + adv + mw + g * 8);
        f32x4 ivn1 = *reinterpret_cast<const f32x4*>(rib + mb + adv + mw + g * 8 + 4);
        // S phase: C-init = l2i -> P = exp2(s' + l2i); lane-local D rows map to m = g*8 + ts*4 + r
        bf16x8 pb[4];
        #pragma unroll
        for (int tt = 0; tt < 4; tt++) {
            f32x4 d0 = __builtin_amdgcn_mfma_f32_16x16x32_bf16(qa[0][0], kf0[tt], iv0, 0, 0, 0);
            d0 = __builtin_amdgcn_mfma_f32_16x16x32_bf16(qa[0][1], kf1[tt], d0, 0, 0, 0);
            f32x4 d1 = __builtin_amdgcn_mfma_f32_16x16x32_bf16(qa[1][0], kf0[tt], iv1, 0, 0, 0);
            d1 = __builtin_amdgcn_mfma_f32_16x16x32_bf16(qa[1][1], kf1[tt], d1, 0, 0, 0);
            float e0 = exp2f(d0[0]);
            float e1 = exp2f(d0[1]);
            float e2 = exp2f(d0[2]);
            float e3 = exp2f(d0[3]);
            float f0 = exp2f(d1[0]);
            float f1 = exp2f(d1[1]);
            float f2 = exp2f(d1[2]);
            float f3 = exp2f(d1[3]);
            unsigned int p0, p1, p2, p3;
            asm("v_cvt_pk_bf16_f32 %0, %1, %2" : "=v"(p0) : "v"(e0), "v"(e1));
            asm("v_cvt_pk_bf16_f32 %0, %1, %2" : "=v"(p1) : "v"(e2), "v"(e3));
            asm("v_cvt_pk_bf16_f32 %0, %1, %2" : "=v"(p2) : "v"(f0), "v"(f1));
            asm("v_cvt_pk_bf16_f32 %0, %1, %2" : "=v"(p3) : "v"(f2), "v"(f3));
            union { unsigned int u[4]; bf16x8 v; } pu;
            pu.u[0] = p0; pu.u[1] = p1; pu.u[2] = p2; pu.u[3] = p3;
            pb[tt] = pu.v;
        }
        // PV phase: full-rate 16x16x32, k = the wave's 32-m slice
        #pragma unroll
        for (int ct = 0; ct < 4; ct++)
            #pragma unroll
            for (int tt = 0; tt < 4; tt++)
                acc[ct][tt] = __builtin_amdgcn_mfma_f32_16x16x32_bf16(va[ct], pb[tt], acc[ct][tt], 0, 0, 0);
        #pragma unroll
        for (int ts = 0; ts < 2; ts++) { qa[ts][0] = qn[ts][0]; qa[ts][1] = qn[ts][1]; }
        iv0 = ivn0; iv1 = ivn1;
        qrp += (size_t)adv * NC;
    }
    // cross-wave reduce (8 partial sums) + bf16 store into padded transposed inP
    #pragma unroll
    for (int ph = 0; ph < 8; ph++) {
        int ct = ph >> 1, th = ph & 1;
        *reinterpret_cast<f32x4*>(&red[w][lane][0]) = acc[ct][th * 2];
        *reinterpret_cast<f32x4*>(&red[w][lane][4]) = acc[ct][th * 2 + 1];
        __syncthreads();
        int lr = t >> 3, kk = t & 7;
        float s = 0.f;
        #pragma unroll
        for (int ww = 0; ww < 8; ww++) s += red[ww][lr][kk];
        int c = ct * 16 + ((lr >> 4) << 2) + (kk & 3);
        int nn = n0 + (th * 2 + (kk >> 2)) * 16 + (lr & 15);
        int y = nn >> 6, xx = nn & 63;
        inP[((size_t)b * PROWS + (size_t)(y + 1) * 66 + 1 + xx) * 64 + c] = f2bf(s);
        __syncthreads();
    }
}

// ---------------- proj conv 3x3 via MFMA: 9 shifted GEMMs
__global__ __launch_bounds__(256) void k_proj_mfma(const unsigned short* __restrict__ inP,
                                                   const unsigned short* __restrict__ wbf,
                                                   float* __restrict__ out) {
    int nb = blockIdx.x, b = blockIdx.y;
    int t = threadIdx.x;
    int w = t >> 6, lane = t & 63, g = lane >> 4, r15 = lane & 15;
    int y = nb >> 1;
    int x0 = (nb & 1) * 32 + (w & 1) * 16;
    int oc0 = (w >> 1) * 32;
    const unsigned short* base = inP + (size_t)b * PROWS * 64;
    f32x4 acc[2] = {{0.f,0.f,0.f,0.f},{0.f,0.f,0.f,0.f}};
    #pragma unroll
    for (int tap = 0; tap < 9; tap++) {
        int dy = tap / 3, dx = tap % 3;
        int p = (y + dy) * 66 + x0 + dx + r15;
        const unsigned short* bp = base + (size_t)p * 64 + g * 8;
        bf16x8 b0 = *reinterpret_cast<const bf16x8*>(bp);
        bf16x8 b1 = *reinterpret_cast<const bf16x8*>(bp + 32);
        #pragma unroll
        for (int tt = 0; tt < 2; tt++) {
            const unsigned short* ap = wbf + tap * 4096 + (size_t)(oc0 + tt * 16 + r15) * 64 + g * 8;
            bf16x8 a0 = *reinterpret_cast<const bf16x8*>(ap);
            bf16x8 a1 = *reinterpret_cast<const bf16x8*>(ap + 32);
            acc[tt] = __builtin_amdgcn_mfma_f32_16x16x32_bf16(a0, b0, acc[tt], 0, 0, 0);
            acc[tt] = __builtin_amdgcn_mfma_f32_16x16x32_bf16(a1, b1, acc[tt], 0, 0, 0);
        }
    }
    int n0 = y * 64 + x0;
    #pragma unroll
    for (int tt = 0; tt < 2; tt++) {
        #pragma unroll
        for (int r = 0; r < 4; r++)
            out[((size_t)b * 64 + oc0 + tt * 16 + g * 4 + r) * HW + n0 + r15] = acc[tt][r];
    }
}

extern "C" void kernel_launch(void* const* d_in, const int* in_sizes, int n_in,
                              void* d_out, int out_size, void* d_ws, size_t ws_size,
                              hipStream_t stream) {
    const float* x    = (const float*)d_in[0];
    const float* wqkv = (const float*)d_in[1];
    const float* wdw  = (const float*)d_in[2];
    const float* wprj = (const float*)d_in[3];
    char* ws = (char*)d_ws;
    float* qkv_raw       = (float*)(ws + 0);          // dead after dwconv
    float* qkv           = (float*)(ws + 12582912);   // dead after pack
    unsigned short* qT   = (unsigned short*)(ws + 25165824);
    unsigned short* kT   = (unsigned short*)(ws + 27262976);
    unsigned short* vn   = (unsigned short*)(ws + 29360128);
    float* psq           = (float*)(ws + 31457280);   // 32,768 B
    float* wk            = (float*)(ws + 31490048);   // 1,024 B
    float* rowsum_part   = (float*)(ws + 31491072);   // 524,288 B (8 partials)
    float* l2i           = (float*)(ws + 32015360);   // 65,536 B
    unsigned short* wbf  = (unsigned short*)(ws + 32080896);  // 73,728 B
    unsigned short* inP  = (unsigned short*)(ws + 32154624);  // 2,230,272 B -> ends 34,384,896

    int inP4 = (4 * PROWS * 64 * 2) / 16;  // 139392 float4
    k_init       <<<dim3(689),        256, 0, stream>>>((float4*)inP, inP4, wprj, wbf);
    k_conv1x1    <<<dim3(16, 24, 4),  256, 0, stream>>>(x, wqkv, qkv_raw);
    k_dwconv     <<<dim3(16, 192, 4), 256, 0, stream>>>(qkv_raw, wdw, qkv, psq);
    k_scales     <<<dim3(1),          256, 0, stream>>>(psq, wk);
    k_pack       <<<dim3(16, 3, 4),   256, 0, stream>>>(qkv, wk, qT, kT, vn);
    k_rowsum     <<<dim3(1024),       256, 0, stream>>>(qT, kT, rowsum_part);
    k_l2i        <<<dim3(64),         256, 0, stream>>>(rowsum_part, l2i);
    k_attn_fused <<<dim3(64, 4),      512, 0, stream>>>(qT, kT, vn, l2i, inP);
    k_proj_mfma  <<<dim3(128, 4),     256, 0, stream>>>(inP, wbf, (float*)d_out);
}